// Round 6
// baseline (1241.517 us; speedup 1.0000x reference)
//
#include <hip/hip_runtime.h>

#define TT 512
#define II 8
#define HH 256
#define ST 296   // padded LDS row stride (halfs): 592B, breaks pow2 bank patterns
#define RR 8     // batch rows per block
#define NB 64    // blocks = 512 / RR
#define XSR 136  // xstage row stride in halfs

typedef _Float16 h4_t  __attribute__((ext_vector_type(4)));
typedef _Float16 h8_t  __attribute__((ext_vector_type(8)));
typedef float    f32x2 __attribute__((ext_vector_type(2)));
typedef float    f32x4 __attribute__((ext_vector_type(4)));

__device__ inline h8_t cvt8(const float* __restrict__ p, float s) {
    h8_t r;
#pragma unroll
    for (int i = 0; i < 8; ++i) r[i] = (_Float16)(p[i] * s);
    return r;
}

// R7: MFMA-pipe model fix. 16x16x32-f16 costs ~19.4 cyc/SIMD (845 F/cyc/SIMD,
// m06), so R6's 108 MFMA/SIMD/step = ~2100 cyc is HALF the 4018-cyc step; the
// other half is the CU-shared LDS pipe (~200KB/CU-step, 2/3 of it the W pools).
// Per-block MFMA volume is invariant (48 chains x K256), so the win is evicting
// LDS W-traffic, not re-spreading. Config: 64 blocks x 256 threads (4 waves,
// 1 wave/SIMD -> 512-VGPR cap). Wave owns 64 cols = 4 groups; 10/12 W chains
// in registers (320 VGPRs), only N1,N3 in LDS pools. Pairs (g0,g1),(g2,g3)
// processed sequentially -> 8 live accs (~434 regs < 450 no-spill line).
// Pair 1 reads A-frags from MIRROR rows (r15^8, identical data) to defeat
// cross-pair load-CSE that would keep 8 A-values live.
// LDS: 18.5K hbuf + 64K pools + 4.25K xstage + 4K predbuf = 92.9K, 1 block/CU.
__global__ void __launch_bounds__(256, 1) gru_kernel(
    const float* __restrict__ x,    const float* __restrict__ W_ih,
    const float* __restrict__ W_hh, const float* __restrict__ b_ih,
    const float* __restrict__ b_hh, const float* __restrict__ W_lin,
    const float* __restrict__ b_lin, float* __restrict__ out)
{
    __shared__ _Float16 hbuf[2][16][ST];
    __shared__ h8_t wn1buf[4 * 8 * 64];     // 32 KiB: group-1 N-gate W frags, lane-private
    __shared__ h8_t wn3buf[4 * 8 * 64];     // 32 KiB: group-3 N-gate W frags, lane-private
    __shared__ _Float16 xstage[2][RR][XSR]; // x windows, double-buffered
    __shared__ float predbuf[2][RR][64];    // pred ring, parity by (p>>6)&1

    const int tid  = threadIdx.x;
    const int w    = tid >> 6;     // wave 0..3
    const int lane = tid & 63;
    const int q    = lane >> 4;    // quad 0..3
    const int r15  = lane & 15;
    const int row0 = blockIdx.x * RR;

    // scales fold log2(e) into the weights:
    //   sigmoid(a) = rcp(1 + exp2(-a*log2e));  tanh(y) = 1 - 2*rcp(1 + exp2(2y*log2e))
    const float sRZ = -1.44269504088896340736f;
    const float sN  =  2.88539008177792681472f;

    // wave w owns gate columns [64w, 64w+64): groups 0..3
    const int c0 = w * 64 + r15;
    const int c1 = c0 + 16;
    const int c2 = c0 + 32;
    const int c3 = c0 + 48;

    // ---- W_hh -> B-fragments (16x16x32_f16: lane holds B[n=lane&15][k=q*8+j]) ----
    // 10 chains in regs (320 VGPRs); N1,N3 -> LDS pools.
    h8_t wfR0[8], wfZ0[8], wfN0[8], wfR1[8], wfZ1[8];
    h8_t wfR2[8], wfZ2[8], wfN2[8], wfR3[8], wfZ3[8];
#pragma unroll
    for (int s = 0; s < 8; ++s) {
        const int k0 = s * 32 + q * 8;
        wfR0[s] = cvt8(W_hh + (size_t)(c0)       * HH + k0, sRZ);
        wfZ0[s] = cvt8(W_hh + (size_t)(256 + c0) * HH + k0, sRZ);
        wfN0[s] = cvt8(W_hh + (size_t)(512 + c0) * HH + k0, sN);
        wfR1[s] = cvt8(W_hh + (size_t)(c1)       * HH + k0, sRZ);
        wfZ1[s] = cvt8(W_hh + (size_t)(256 + c1) * HH + k0, sRZ);
        wfR2[s] = cvt8(W_hh + (size_t)(c2)       * HH + k0, sRZ);
        wfZ2[s] = cvt8(W_hh + (size_t)(256 + c2) * HH + k0, sRZ);
        wfN2[s] = cvt8(W_hh + (size_t)(512 + c2) * HH + k0, sN);
        wfR3[s] = cvt8(W_hh + (size_t)(c3)       * HH + k0, sRZ);
        wfZ3[s] = cvt8(W_hh + (size_t)(256 + c3) * HH + k0, sRZ);
        wn1buf[(w * 8 + s) * 64 + lane] = cvt8(W_hh + (size_t)(512 + c1) * HH + k0, sN);
        wn3buf[(w * 8 + s) * 64 + lane] = cvt8(W_hh + (size_t)(512 + c3) * HH + k0, sN);
    }
    // ---- x-part B-fragments (16x16x16f16) over [x(8)|bias(1)|0..] for all 4 groups ----
    const int cga[4] = {c0, c1, c2, c3};
    h4_t xfR[4], xfZ[4], xfN[4];
#pragma unroll
    for (int g = 0; g < 4; ++g) {
        const int cR = cga[g];
#pragma unroll
        for (int j = 0; j < 4; ++j) {
            const int kp = q * 4 + j;
            float vR = 0.f, vZ = 0.f, vN = 0.f;
            if (kp < 8) {
                vR = W_ih[(cR)       * II + kp] * sRZ;
                vZ = W_ih[(256 + cR) * II + kp] * sRZ;
                vN = W_ih[(512 + cR) * II + kp] * sN;
            } else if (kp == 8) {
                vR = (b_ih[cR]       + b_hh[cR])       * sRZ;
                vZ = (b_ih[256 + cR] + b_hh[256 + cR]) * sRZ;
                vN = b_ih[512 + cR] * sN;   // b_hh_n rides inside r*(.), kept separate
            }
            xfR[g][j] = (_Float16)vR; xfZ[g][j] = (_Float16)vZ; xfN[g][j] = (_Float16)vN;
        }
    }
    // per-lane gate constants: lanes 0-31 -> even group, lanes 32-63 -> odd group
    const bool hi = (lane >= 32);
    const float bhnp0 = (hi ? b_hh[512 + c1] : b_hh[512 + c0]) * sN;
    const float bhnp1 = (hi ? b_hh[512 + c3] : b_hh[512 + c2]) * sN;
    const float blin = b_lin[0];
    // pred: half-wave reduces one row; lane holds W_lin[(lane&31)*8 .. +7]
    const int l31  = lane & 31;
    const int prow = w + (lane >> 5) * 4;     // rows w and w+4
    float wl[8];
#pragma unroll
    for (int i = 0; i < 8; ++i) wl[i] = W_lin[l31 * 8 + i];

    // A-frag constants for the x-part (k'=q*4+j): q=2 holds bias-one at k'=8
    const h4_t bias4 = {(_Float16)1.f, (_Float16)0.f, (_Float16)0.f, (_Float16)0.f};
    const h4_t zero4 = {(_Float16)0.f, (_Float16)0.f, (_Float16)0.f, (_Float16)0.f};

    // ---- LDS init: zero h buffers; preload x window 0 (steps 0..15) ----
    for (int i = tid; i < 2 * 16 * ST; i += 256) (&hbuf[0][0][0])[i] = (_Float16)0.f;
    const int xrow = tid >> 5, xf4 = (tid & 31) * 4;   // 256 thr x 4 floats = 1024
    {
        const f32x4 v = *(const f32x4*)(x + (size_t)(row0 + xrow) * TT * II + xf4);
        xstage[0][xrow][xf4]     = (_Float16)v[0];
        xstage[0][xrow][xf4 + 1] = (_Float16)v[1];
        xstage[0][xrow][xf4 + 2] = (_Float16)v[2];
        xstage[0][xrow][xf4 + 3] = (_Float16)v[3];
    }
    __syncthreads();

    const h8_t* __restrict__ wn1_lane = &wn1buf[w * 8 * 64 + lane];
    const h8_t* __restrict__ wn3_lane = &wn3buf[w * 8 * 64 + lane];

    f32x4 hreg0 = {0.f, 0.f, 0.f, 0.f};   // pair 0: h at (rb+j, hi?c1:c0)
    f32x4 hreg1 = {0.f, 0.f, 0.f, 0.f};   // pair 1: h at (rb+j, hi?c3:c2)
    const f32x4 z4 = {0.f, 0.f, 0.f, 0.f};

    const int rb = (q & 1) * 4;            // packed row base
    f32x4 xpre = {0.f, 0.f, 0.f, 0.f};     // x refill staging regs

    for (int t = 0; t < TT; ++t) {
        const int cur = t & 1, nxt = cur ^ 1;
        const int win = (t >> 4) & 1;

        // x window refill: issue load at window start, consumed 15 steps later
        if ((t & 15) == 0 && t + 16 < TT) {
            xpre = *(const f32x4*)(x + ((size_t)(row0 + xrow) * TT + (t + 16)) * II + xf4);
        }

        const h4_t xa = *(const h4_t*)&xstage[win][r15 & 7][(t & 15) * 8 + (q & 1) * 4];
        const h4_t a2 = (q < 2) ? xa : ((q == 2) ? bias4 : zero4);

        // ---- pair 0: groups 0 (lanes 0-31) / 1 (lanes 32-63) ----
        {
            const _Float16* hb = &hbuf[cur][r15][0];
            f32x4 aR0 = __builtin_amdgcn_mfma_f32_16x16x16f16(a2, xfR[0], z4, 0, 0, 0);
            f32x4 aZ0 = __builtin_amdgcn_mfma_f32_16x16x16f16(a2, xfZ[0], z4, 0, 0, 0);
            f32x4 gi0 = __builtin_amdgcn_mfma_f32_16x16x16f16(a2, xfN[0], z4, 0, 0, 0);
            f32x4 aR1 = __builtin_amdgcn_mfma_f32_16x16x16f16(a2, xfR[1], z4, 0, 0, 0);
            f32x4 aZ1 = __builtin_amdgcn_mfma_f32_16x16x16f16(a2, xfZ[1], z4, 0, 0, 0);
            f32x4 gi1 = __builtin_amdgcn_mfma_f32_16x16x16f16(a2, xfN[1], z4, 0, 0, 0);
            f32x4 aN0 = z4, aN1 = z4;
#pragma unroll
            for (int s = 0; s < 8; ++s) {
                const h8_t a  = *(const h8_t*)(hb + s * 32 + q * 8);
                const h8_t wn = wn1_lane[s * 64];
                aR0 = __builtin_amdgcn_mfma_f32_16x16x32_f16(a, wfR0[s], aR0, 0, 0, 0);
                aZ0 = __builtin_amdgcn_mfma_f32_16x16x32_f16(a, wfZ0[s], aZ0, 0, 0, 0);
                aN0 = __builtin_amdgcn_mfma_f32_16x16x32_f16(a, wfN0[s], aN0, 0, 0, 0);
                aR1 = __builtin_amdgcn_mfma_f32_16x16x32_f16(a, wfR1[s], aR1, 0, 0, 0);
                aZ1 = __builtin_amdgcn_mfma_f32_16x16x32_f16(a, wfZ1[s], aZ1, 0, 0, 0);
                aN1 = __builtin_amdgcn_mfma_f32_16x16x32_f16(a, wn,     aN1, 0, 0, 0);
            }
            _Float16* hw = &hbuf[nxt][rb][hi ? c1 : c0];
#pragma unroll
            for (int j = 0; j < 4; ++j) {
                const float vR = hi ? aR1[j] : aR0[j];
                const float vZ = hi ? aZ1[j] : aZ0[j];
                const float vN = hi ? aN1[j] : aN0[j];
                const float vG = hi ? gi1[j] : gi0[j];
                const float rr = __builtin_amdgcn_rcpf(1.f + __builtin_amdgcn_exp2f(vR));
                const float zz = __builtin_amdgcn_rcpf(1.f + __builtin_amdgcn_exp2f(vZ));
                const float u  = vG + rr * (vN + bhnp0);
                const float nn = 1.f - 2.f * __builtin_amdgcn_rcpf(1.f + __builtin_amdgcn_exp2f(u));
                const float hv = nn + zz * (hreg0[j] - nn);
                hreg0[j] = hv;
                const _Float16 hh = (_Float16)hv;
                hw[j * ST]          = hh;
                hw[j * ST + 8 * ST] = hh;   // mirror
            }
        }

        // pred_{t-1} = h_{t-1}.W_lin + b_lin (overlaps pair-1 MFMAs below).
        // half-wave reduces one row: lanes 0-31 -> row w, 32-63 -> row w+4.
        if (t > 0) {
            const h8_t hv8 = *(const h8_t*)&hbuf[cur][prow][l31 * 8];
            float s0 = 0.f;
#pragma unroll
            for (int i = 0; i < 8; ++i) s0 += (float)hv8[i] * wl[i];
#pragma unroll
            for (int m = 16; m >= 1; m >>= 1) s0 += __shfl_xor(s0, m, 64);
            if (l31 == 0) predbuf[((t - 1) >> 6) & 1][prow][(t - 1) & 63] = s0 + blin;
        }

        // ---- pair 1: groups 2 (lanes 0-31) / 3 (lanes 32-63) ----
        // A-frags read from MIRROR rows (r15^8): identical data, distinct
        // addresses -> no cross-pair load-CSE keeping 8 A-values live.
        {
            const _Float16* hb = &hbuf[cur][r15 ^ 8][0];
            f32x4 aR2 = __builtin_amdgcn_mfma_f32_16x16x16f16(a2, xfR[2], z4, 0, 0, 0);
            f32x4 aZ2 = __builtin_amdgcn_mfma_f32_16x16x16f16(a2, xfZ[2], z4, 0, 0, 0);
            f32x4 gi2 = __builtin_amdgcn_mfma_f32_16x16x16f16(a2, xfN[2], z4, 0, 0, 0);
            f32x4 aR3 = __builtin_amdgcn_mfma_f32_16x16x16f16(a2, xfR[3], z4, 0, 0, 0);
            f32x4 aZ3 = __builtin_amdgcn_mfma_f32_16x16x16f16(a2, xfZ[3], z4, 0, 0, 0);
            f32x4 gi3 = __builtin_amdgcn_mfma_f32_16x16x16f16(a2, xfN[3], z4, 0, 0, 0);
            f32x4 aN2 = z4, aN3 = z4;
#pragma unroll
            for (int s = 0; s < 8; ++s) {
                const h8_t a  = *(const h8_t*)(hb + s * 32 + q * 8);
                const h8_t wn = wn3_lane[s * 64];
                aR2 = __builtin_amdgcn_mfma_f32_16x16x32_f16(a, wfR2[s], aR2, 0, 0, 0);
                aZ2 = __builtin_amdgcn_mfma_f32_16x16x32_f16(a, wfZ2[s], aZ2, 0, 0, 0);
                aN2 = __builtin_amdgcn_mfma_f32_16x16x32_f16(a, wfN2[s], aN2, 0, 0, 0);
                aR3 = __builtin_amdgcn_mfma_f32_16x16x32_f16(a, wfR3[s], aR3, 0, 0, 0);
                aZ3 = __builtin_amdgcn_mfma_f32_16x16x32_f16(a, wfZ3[s], aZ3, 0, 0, 0);
                aN3 = __builtin_amdgcn_mfma_f32_16x16x32_f16(a, wn,     aN3, 0, 0, 0);
            }
            _Float16* hw = &hbuf[nxt][rb][hi ? c3 : c2];
#pragma unroll
            for (int j = 0; j < 4; ++j) {
                const float vR = hi ? aR3[j] : aR2[j];
                const float vZ = hi ? aZ3[j] : aZ2[j];
                const float vN = hi ? aN3[j] : aN2[j];
                const float vG = hi ? gi3[j] : gi2[j];
                const float rr = __builtin_amdgcn_rcpf(1.f + __builtin_amdgcn_exp2f(vR));
                const float zz = __builtin_amdgcn_rcpf(1.f + __builtin_amdgcn_exp2f(vZ));
                const float u  = vG + rr * (vN + bhnp1);
                const float nn = 1.f - 2.f * __builtin_amdgcn_rcpf(1.f + __builtin_amdgcn_exp2f(u));
                const float hv = nn + zz * (hreg1[j] - nn);
                hreg1[j] = hv;
                const _Float16 hh = (_Float16)hv;
                hw[j * ST]          = hh;
                hw[j * ST + 8 * ST] = hh;   // mirror
            }
        }

        // x window writeback: cvt + ds_write into the other buffer
        if ((t & 15) == 15 && t + 1 < TT) {
            _Float16* xd = &xstage[win ^ 1][xrow][xf4];
            xd[0] = (_Float16)xpre[0];
            xd[1] = (_Float16)xpre[1];
            xd[2] = (_Float16)xpre[2];
            xd[3] = (_Float16)xpre[3];
        }

        __syncthreads();   // single barrier per step

        // coalesced pred flush: 2KB per 64 steps
        if ((t & 63) == 0 && t > 0) {
            const int pb = ((t >> 6) & 1) ^ 1;
            const int pr = tid >> 5, cc = (tid & 31) * 2;
            f32x2 pv;
            pv[0] = predbuf[pb][pr][cc];
            pv[1] = predbuf[pb][pr][cc + 1];
            *(f32x2*)&out[(size_t)(row0 + pr) * TT + (t - 64) + cc] = pv;
        }
    }

    // final pred for t = TT-1 (h_final sits in hbuf[TT & 1] = hbuf[0])
    {
        const h8_t hv8 = *(const h8_t*)&hbuf[TT & 1][prow][l31 * 8];
        float s0 = 0.f;
#pragma unroll
        for (int i = 0; i < 8; ++i) s0 += (float)hv8[i] * wl[i];
#pragma unroll
        for (int m = 16; m >= 1; m >>= 1) s0 += __shfl_xor(s0, m, 64);
        if (l31 == 0) predbuf[1][prow][63] = s0 + blin;
    }
    __syncthreads();
    // flush last chunk [448, 512)
    {
        const int pr = tid >> 5, cc = (tid & 31) * 2;
        f32x2 pv;
        pv[0] = predbuf[1][pr][cc];
        pv[1] = predbuf[1][pr][cc + 1];
        *(f32x2*)&out[(size_t)(row0 + pr) * TT + 448 + cc] = pv;
    }
}

extern "C" void kernel_launch(void* const* d_in, const int* in_sizes, int n_in,
                              void* d_out, int out_size, void* d_ws, size_t ws_size,
                              hipStream_t stream) {
    const float* x     = (const float*)d_in[0];
    const float* W_ih  = (const float*)d_in[1];
    const float* W_hh  = (const float*)d_in[2];
    const float* b_ih  = (const float*)d_in[3];
    const float* b_hh  = (const float*)d_in[4];
    const float* W_lin = (const float*)d_in[5];
    const float* b_lin = (const float*)d_in[6];
    float* out = (float*)d_out;
    gru_kernel<<<NB, 256, 0, stream>>>(x, W_ih, W_hh, b_ih, b_hh, W_lin, b_lin, out);
}

// Round 9
// 823.912 us; speedup vs baseline: 1.5069x; 1.5069x over previous
//
#include <hip/hip_runtime.h>

#define TT 512
#define II 8
#define HH 256
#define ST 296   // padded LDS row stride (halfs): 592B, breaks pow2 bank patterns
#define RR 8     // batch rows per block
#define NB 64    // blocks = 512 / RR
#define XSR 136  // xstage row stride in halfs

typedef _Float16 h4_t  __attribute__((ext_vector_type(4)));
typedef _Float16 h8_t  __attribute__((ext_vector_type(8)));
typedef float    f32x2 __attribute__((ext_vector_type(2)));
typedef float    f32x4 __attribute__((ext_vector_type(4)));

__device__ inline h8_t cvt8(const float* __restrict__ p, float s) {
    h8_t r;
#pragma unroll
    for (int i = 0; i < 8; ++i) r[i] = (_Float16)(p[i] * s);
    return r;
}

// R9: verified-R6 math, restructured loop. R8's all-W-in-regs failed: the
// measured allocator rule is VGPR cap = AGPR cap = 256/min_waves_per_EU
// ((1024,4)->64+64, (512,2)->128+128; R3's 160-reg W set spilled), so 192 W
// regs can't fit 128 AGPRs at (512,2). R6 (857us) already sits at the AGPR
// sweet spot: 4 chains in AGPR + 2 chains in LDS pools. Remaining fat per
// R6 counters: VALUBusy ~1400 cyc/SIMD/step vs ~400 of real gate/pred math
// -> ~1000 cyc of per-step address/select/branch recomputation (cur/nxt/win
// pointer selects, (t&15) branches, xa offset math x512 steps).
// Fix: 32 windows x 16 fully-unrolled steps. cur = ti&1 is COMPILE-TIME:
// pointer pairs hoisted once; xa offsets become immediates; refill (ti==0),
// writeback (ti==15), pred-flush (ti==0 && tw%4==0) conditions fold away.
// Gate math, MFMA chains, LDS layout byte-identical to R6-verified.
__global__ void __launch_bounds__(512, 2) gru_kernel(
    const float* __restrict__ x,    const float* __restrict__ W_ih,
    const float* __restrict__ W_hh, const float* __restrict__ b_ih,
    const float* __restrict__ b_hh, const float* __restrict__ W_lin,
    const float* __restrict__ b_lin, float* __restrict__ out)
{
    __shared__ _Float16 hbuf[2][16][ST];
    __shared__ h8_t wz1buf[8 * 8 * 64];     // 64 KiB: group-1 Z-gate W frags, lane-private
    __shared__ h8_t wn1buf[8 * 8 * 64];     // 64 KiB: group-1 N-gate W frags, lane-private
    __shared__ _Float16 xstage[2][RR][XSR]; // x windows, double-buffered
    __shared__ float predbuf[2][RR][64];    // pred ring, parity by (p>>6)&1

    const int tid  = threadIdx.x;
    const int w    = tid >> 6;     // wave 0..7
    const int lane = tid & 63;
    const int q    = lane >> 4;    // quad 0..3
    const int r15  = lane & 15;
    const int row0 = blockIdx.x * RR;

    // scales fold log2(e) into the weights:
    //   sigmoid(a) = rcp(1 + exp2(-a*log2e));  tanh(y) = 1 - 2*rcp(1 + exp2(2y*log2e))
    const float sRZ = -1.44269504088896340736f;
    const float sN  =  2.88539008177792681472f;

    const int c0 = w * 32 + r15;
    const int c1 = c0 + 16;

    // ---- W_hh -> B-fragments: 4 chains in regs->AGPR (128), Z1/N1 in LDS pools ----
    h8_t wfR0[8], wfZ0[8], wfN0[8], wfR1[8];
#pragma unroll
    for (int s = 0; s < 8; ++s) {
        const int k0 = s * 32 + q * 8;
        wfR0[s] = cvt8(W_hh + (size_t)(c0)       * HH + k0, sRZ);
        wfZ0[s] = cvt8(W_hh + (size_t)(256 + c0) * HH + k0, sRZ);
        wfN0[s] = cvt8(W_hh + (size_t)(512 + c0) * HH + k0, sN);
        wfR1[s] = cvt8(W_hh + (size_t)(c1)       * HH + k0, sRZ);
        wz1buf[(w * 8 + s) * 64 + lane] = cvt8(W_hh + (size_t)(256 + c1) * HH + k0, sRZ);
        wn1buf[(w * 8 + s) * 64 + lane] = cvt8(W_hh + (size_t)(512 + c1) * HH + k0, sN);
    }
    // ---- x-part B-fragments (16x16x16f16) over [x(8)|bias(1)|0..] ----
    h4_t xfR[2], xfZ[2], xfN[2];
#pragma unroll
    for (int g = 0; g < 2; ++g) {
        const int cR = g ? c1 : c0;
#pragma unroll
        for (int j = 0; j < 4; ++j) {
            const int kp = q * 4 + j;
            float vR = 0.f, vZ = 0.f, vN = 0.f;
            if (kp < 8) {
                vR = W_ih[(cR)       * II + kp] * sRZ;
                vZ = W_ih[(256 + cR) * II + kp] * sRZ;
                vN = W_ih[(512 + cR) * II + kp] * sN;
            } else if (kp == 8) {
                vR = (b_ih[cR]       + b_hh[cR])       * sRZ;
                vZ = (b_ih[256 + cR] + b_hh[256 + cR]) * sRZ;
                vN = b_ih[512 + cR] * sN;   // b_hh_n rides inside r*(.), kept separate
            }
            xfR[g][j] = (_Float16)vR; xfZ[g][j] = (_Float16)vZ; xfN[g][j] = (_Float16)vN;
        }
    }
    const bool hi = (lane >= 32);
    const float bhnp = (hi ? b_hh[512 + c1] : b_hh[512 + c0]) * sN;
    const float blin = b_lin[0];
    const float wl0 = W_lin[lane * 4 + 0], wl1 = W_lin[lane * 4 + 1];
    const float wl2 = W_lin[lane * 4 + 2], wl3 = W_lin[lane * 4 + 3];

    const h4_t bias4 = {(_Float16)1.f, (_Float16)0.f, (_Float16)0.f, (_Float16)0.f};
    const h4_t zero4 = {(_Float16)0.f, (_Float16)0.f, (_Float16)0.f, (_Float16)0.f};

    // ---- LDS init: zero h buffers; preload x window 0 (steps 0..15) ----
    for (int i = tid; i < 2 * 16 * ST; i += 512) (&hbuf[0][0][0])[i] = (_Float16)0.f;
    const int xrow = tid >> 6, xf2 = (tid & 63) * 2;
    {
        const f32x2 v = *(const f32x2*)(x + (size_t)(row0 + xrow) * TT * II + xf2);
        xstage[0][xrow][xf2]     = (_Float16)v[0];
        xstage[0][xrow][xf2 + 1] = (_Float16)v[1];
    }
    __syncthreads();

    const h8_t* __restrict__ wz_lane = &wz1buf[w * 8 * 64 + lane];
    const h8_t* __restrict__ wn_lane = &wn1buf[w * 8 * 64 + lane];

    f32x4 hreg = {0.f, 0.f, 0.f, 0.f};
    const f32x4 z4 = {0.f, 0.f, 0.f, 0.f};

    const int rb   = (q & 1) * 4;
    const int colp = hi ? c1 : c0;

    // hoisted pointer pairs (selected by compile-time ti&1 after unroll)
    const _Float16* __restrict__ hbA0 = &hbuf[0][r15][0];
    const _Float16* __restrict__ hbA1 = &hbuf[1][r15][0];
    const _Float16* __restrict__ pr0  = &hbuf[0][w][lane * 4];
    const _Float16* __restrict__ pr1  = &hbuf[1][w][lane * 4];
    _Float16* __restrict__ hw0 = &hbuf[0][rb][colp];
    _Float16* __restrict__ hw1 = &hbuf[1][rb][colp];
    const _Float16* __restrict__ xsl0 = &xstage[0][r15 & 7][(q & 1) * 4];
    const _Float16* __restrict__ xsl1 = &xstage[1][r15 & 7][(q & 1) * 4];
    _Float16* __restrict__ xw0 = &xstage[0][xrow][xf2];
    _Float16* __restrict__ xw1 = &xstage[1][xrow][xf2];
    const float* __restrict__ xrp = x + ((size_t)(row0 + xrow) * TT + 16) * II + xf2;

    for (int tw = 0; tw < 32; ++tw) {
        const _Float16* __restrict__ xs_rd = (tw & 1) ? xsl1 : xsl0;
        _Float16* __restrict__ xs_wr = (tw & 1) ? xw0 : xw1;   // other buffer

        // window refill: one load, consumed at ti==15
        f32x2 xpre = {0.f, 0.f};
        if (tw < 31) xpre = *(const f32x2*)xrp;

#pragma unroll
        for (int ti = 0; ti < 16; ++ti) {
            const int t = tw * 16 + ti;
            const int cur = ti & 1;

            const _Float16* __restrict__ hb = cur ? hbA1 : hbA0;
            const h4_t xa = *(const h4_t*)(xs_rd + ti * 8);
            const h4_t a2 = (q < 2) ? xa : ((q == 2) ? bias4 : zero4);
            f32x4 accR0 = __builtin_amdgcn_mfma_f32_16x16x16f16(a2, xfR[0], z4, 0, 0, 0);
            f32x4 accZ0 = __builtin_amdgcn_mfma_f32_16x16x16f16(a2, xfZ[0], z4, 0, 0, 0);
            f32x4 gin0  = __builtin_amdgcn_mfma_f32_16x16x16f16(a2, xfN[0], z4, 0, 0, 0);
            f32x4 accR1 = __builtin_amdgcn_mfma_f32_16x16x16f16(a2, xfR[1], z4, 0, 0, 0);
            f32x4 accZ1 = __builtin_amdgcn_mfma_f32_16x16x16f16(a2, xfZ[1], z4, 0, 0, 0);
            f32x4 gin1  = __builtin_amdgcn_mfma_f32_16x16x16f16(a2, xfN[1], z4, 0, 0, 0);
            f32x4 accN0 = z4, accN1 = z4;
#pragma unroll
            for (int s = 0; s < 8; ++s) {
                const h8_t a  = *(const h8_t*)(hb + s * 32 + q * 8);
                const h8_t wz = wz_lane[s * 64];
                const h8_t wn = wn_lane[s * 64];
                accR0 = __builtin_amdgcn_mfma_f32_16x16x32_f16(a, wfR0[s], accR0, 0, 0, 0);
                accZ0 = __builtin_amdgcn_mfma_f32_16x16x32_f16(a, wfZ0[s], accZ0, 0, 0, 0);
                accN0 = __builtin_amdgcn_mfma_f32_16x16x32_f16(a, wfN0[s], accN0, 0, 0, 0);
                accR1 = __builtin_amdgcn_mfma_f32_16x16x32_f16(a, wfR1[s], accR1, 0, 0, 0);
                accZ1 = __builtin_amdgcn_mfma_f32_16x16x32_f16(a, wz,     accZ1, 0, 0, 0);
                accN1 = __builtin_amdgcn_mfma_f32_16x16x32_f16(a, wn,     accN1, 0, 0, 0);
            }

            // pred_{t-1} from hbuf[cur] (overlaps MFMA drain) -> LDS ring
            if (t > 0) {
                const h4_t hv4 = *(const h4_t*)(cur ? pr1 : pr0);
                float s0 = (float)hv4[0] * wl0 + (float)hv4[1] * wl1
                         + (float)hv4[2] * wl2 + (float)hv4[3] * wl3;
#pragma unroll
                for (int m = 32; m >= 1; m >>= 1) s0 += __shfl_xor(s0, m, 64);
                if (lane == 0) predbuf[((t - 1) >> 6) & 1][w][(t - 1) & 63] = s0 + blin;
            }

            // gates, dense packed (lanes 0-31 g0, 32-63 g1)
            _Float16* __restrict__ hw = cur ? hw0 : hw1;   // writes to buffer nxt=cur^1
#pragma unroll
            for (int j = 0; j < 4; ++j) {
                const float vR = hi ? accR1[j] : accR0[j];
                const float vZ = hi ? accZ1[j] : accZ0[j];
                const float vN = hi ? accN1[j] : accN0[j];
                const float vG = hi ? gin1[j]  : gin0[j];
                const float rr = __builtin_amdgcn_rcpf(1.f + __builtin_amdgcn_exp2f(vR));
                const float zz = __builtin_amdgcn_rcpf(1.f + __builtin_amdgcn_exp2f(vZ));
                const float u  = vG + rr * (vN + bhnp);
                const float nn = 1.f - 2.f * __builtin_amdgcn_rcpf(1.f + __builtin_amdgcn_exp2f(u));
                const float hv = nn + zz * (hreg[j] - nn);
                hreg[j] = hv;
                const _Float16 hh = (_Float16)hv;
                hw[j * ST]          = hh;
                hw[j * ST + 8 * ST] = hh;   // mirror rows 8-15
            }

            // x window writeback into the other buffer (load issued at tw start)
            if (ti == 15 && tw < 31) {
                xs_wr[0] = (_Float16)xpre[0];
                xs_wr[1] = (_Float16)xpre[1];
            }

            __syncthreads();   // single barrier per step

            // coalesced pred flush: one 2KB store per 64 steps
            if (ti == 0 && (tw & 3) == 0 && tw > 0) {
                const int pb = ((t >> 6) & 1) ^ 1;
                out[(size_t)(row0 + (tid >> 6)) * TT + (t - 64) + (tid & 63)] =
                    predbuf[pb][tid >> 6][tid & 63];
            }
        }
        xrp += 16 * II;
    }

    // final pred for t = TT-1 (h_final sits in hbuf[0])
    {
        const h4_t hv4 = *(const h4_t*)pr0;
        float s0 = (float)hv4[0] * wl0 + (float)hv4[1] * wl1
                 + (float)hv4[2] * wl2 + (float)hv4[3] * wl3;
#pragma unroll
        for (int m = 32; m >= 1; m >>= 1) s0 += __shfl_xor(s0, m, 64);
        if (lane == 0) predbuf[1][w][63] = s0 + blin;
    }
    __syncthreads();
    // flush last chunk [448, 512)
    out[(size_t)(row0 + (tid >> 6)) * TT + 448 + (tid & 63)] =
        predbuf[1][tid >> 6][tid & 63];
}

extern "C" void kernel_launch(void* const* d_in, const int* in_sizes, int n_in,
                              void* d_out, int out_size, void* d_ws, size_t ws_size,
                              hipStream_t stream) {
    const float* x     = (const float*)d_in[0];
    const float* W_ih  = (const float*)d_in[1];
    const float* W_hh  = (const float*)d_in[2];
    const float* b_ih  = (const float*)d_in[3];
    const float* b_hh  = (const float*)d_in[4];
    const float* W_lin = (const float*)d_in[5];
    const float* b_lin = (const float*)d_in[6];
    float* out = (float*)d_out;
    gru_kernel<<<NB, 512, 0, stream>>>(x, W_ih, W_hh, b_ih, b_hh, W_lin, b_lin, out);
}